// Round 9
// baseline (334.198 us; speedup 1.0000x reference)
//
#include <hip/hip_runtime.h>

typedef __attribute__((ext_vector_type(8))) short short8;
typedef __attribute__((ext_vector_type(4))) short s16x4;
typedef __attribute__((ext_vector_type(4))) float f32x4;
typedef unsigned short ushort;

#define S_LEN 2048
#define D_MODEL 2048
#define NH 16
#define HD 128

__device__ __forceinline__ float b2f(ushort u) {
  union { unsigned int i; float f; } v; v.i = ((unsigned int)u) << 16; return v.f;
}
__device__ __forceinline__ ushort f2b(float f) {
  union { float f; unsigned int i; } v; v.f = f;
  unsigned int r = v.i + 0x7FFFu + ((v.i >> 16) & 1u);
  return (ushort)(r >> 16);
}
__device__ __forceinline__ ushort f2b_trunc(float f) {
  union { float f; unsigned int i; } v; v.f = f;
  return (ushort)(v.i >> 16);
}

__device__ __forceinline__ void gload_lds16(const void* g, void* l) {
  __builtin_amdgcn_global_load_lds(
      (const __attribute__((address_space(1))) void*)g,
      (__attribute__((address_space(3))) void*)l, 16, 0, 0);
}

// ===========================================================================
// QKV GEMM (bf16, global_load_lds, XOR swizzle), fused RoPE/IA3 epilogue.
// C = A @ B^T over K=2048, 128x128 tiles.
//   n0 <  4096 (Q/K): B-frag col remap puts the RoPE pair (d, d+64) in
//     acc[i][j]/acc[i][j+2] of the same lane; RoPE applied in-register using
//     TRANSPOSED tables cosT/sinT[hd][s] (f32x4 over 4 consecutive s).
//     Q additionally scaled by l_k * 1/sqrt(128) * log2(e).
//   n0 >= 4096 (V): write V^T (l_v folded) as (h*128+d)*6144 + 4096 + s.
// ===========================================================================
__global__ __launch_bounds__(256)
void gemm_qkv_b(const ushort* __restrict__ A, const ushort* __restrict__ B,
                ushort* __restrict__ C, const float* __restrict__ lv,
                const float* __restrict__ cosT, const float* __restrict__ sinT,
                const float* __restrict__ lk)
{
  __shared__ ushort lA[128 * 64];
  __shared__ ushort lB[128 * 64];
  const int tid  = threadIdx.x;
  const int lane = tid & 63;
  const int wave = tid >> 6;
  const int quad = lane >> 4;
  const int l15  = lane & 15;
  const int wm   = wave >> 1;
  const int wn   = wave & 1;
  const int m0   = blockIdx.y * 128;
  const int n0   = blockIdx.x * 128;

  const bool isV = (n0 >= 4096);
  int bcol[4];
#pragma unroll
  for (int j = 0; j < 4; ++j)
    bcol[j] = isV ? (wn * 64 + j * 16)
                  : (wn * 32 + (j & 1) * 16 + (j >> 1) * 64);

  f32x4 acc[4][4];
#pragma unroll
  for (int i = 0; i < 4; ++i)
#pragma unroll
    for (int j = 0; j < 4; ++j)
      acc[i][j] = (f32x4){0.f, 0.f, 0.f, 0.f};

  const int srow0 = wave * 8 + (lane >> 3);
  const int cph   = lane & 7;

  for (int kt = 0; kt < 32; ++kt) {
    __syncthreads();
#pragma unroll
    for (int j = 0; j < 4; ++j) {
      const int row = j * 32 + srow0;
      const int gc  = cph ^ (row & 7);
      gload_lds16(A + (size_t)(m0 + row) * 2048 + kt * 64 + gc * 8,
                  &lA[row * 64 + cph * 8]);
      gload_lds16(B + (size_t)(n0 + row) * 2048 + kt * 64 + gc * 8,
                  &lB[row * 64 + cph * 8]);
    }
    __syncthreads();
#pragma unroll
    for (int kk = 0; kk < 2; ++kk) {
      short8 af[4], bfr[4];
#pragma unroll
      for (int i = 0; i < 4; ++i) {
        const int r = wm * 64 + i * 16 + l15;
        af[i] = *(const short8*)&lA[r * 64 + (((kk * 4 + quad) ^ (l15 & 7)) * 8)];
      }
#pragma unroll
      for (int j = 0; j < 4; ++j) {
        const int r = bcol[j] + l15;
        bfr[j] = *(const short8*)&lB[r * 64 + (((kk * 4 + quad) ^ (l15 & 7)) * 8)];
      }
#pragma unroll
      for (int i = 0; i < 4; ++i)
#pragma unroll
        for (int j = 0; j < 4; ++j)
          acc[i][j] = __builtin_amdgcn_mfma_f32_16x16x32_bf16(af[i], bfr[j], acc[i][j], 0, 0, 0);
    }
  }

  if (isV) {
#pragma unroll
    for (int j = 0; j < 4; ++j)
#pragma unroll
      for (int i = 0; i < 4; ++i) {
        const int vcol = n0 - 4096 + bcol[j] + l15;
        const float sc = lv[vcol];
        const int sb   = m0 + wm * 64 + i * 16 + quad * 4;
        s16x4 pk;
#pragma unroll
        for (int r = 0; r < 4; ++r) pk[r] = (short)f2b(acc[i][j][r] * sc);
        *(s16x4*)&C[(size_t)vcol * 6144 + 4096 + sb] = pk;
      }
    return;
  }

  // Q/K: in-register RoPE with transposed tables
  const bool isQ = (n0 < 2048);
  const int hb = n0 & 2047;  // head*128
  const float qsc = 0.08838834764831845f * 1.4426950408889634f;
#pragma unroll
  for (int j = 0; j < 2; ++j) {
    const int d_lo = bcol[j] + l15;       // [0,64)
    const int d_hi = d_lo + 64;           // matches bcol[j+2]+l15
    const float sl_lo = isQ ? lk[hb + d_lo] * qsc : 1.f;
    const float sl_hi = isQ ? lk[hb + d_hi] * qsc : 1.f;
#pragma unroll
    for (int i = 0; i < 4; ++i) {
      const int sb = m0 + wm * 64 + i * 16 + quad * 4;   // 4 consecutive s
      const f32x4 cl = *(const f32x4*)&cosT[d_lo * 2048 + sb];
      const f32x4 sl = *(const f32x4*)&sinT[d_lo * 2048 + sb];
      const f32x4 ch = *(const f32x4*)&cosT[d_hi * 2048 + sb];
      const f32x4 sh = *(const f32x4*)&sinT[d_hi * 2048 + sb];
#pragma unroll
      for (int r = 0; r < 4; ++r) {
        const float lo = acc[i][j][r];
        const float hi = acc[i][j + 2][r];
        float o_lo = lo * cl[r] - hi * sl[r];
        float o_hi = hi * ch[r] + lo * sh[r];
        if (isQ) { o_lo *= sl_lo; o_hi *= sl_hi; }
        const int s = sb + r;
        C[(size_t)s * 6144 + n0 + d_lo] = f2b(o_lo);
        C[(size_t)s * 6144 + n0 + d_hi] = f2b(o_hi);
      }
    }
  }
}

// ===========================================================================
// Output GEMM: 128x64 tiles -> 512 blocks (2/CU), f32 direct store.
// ===========================================================================
__global__ __launch_bounds__(256)
void gemm_wo_64(const ushort* __restrict__ A, const ushort* __restrict__ B,
                float* __restrict__ C)
{
  __shared__ ushort lA[128 * 64];
  __shared__ ushort lB[64 * 64];
  const int tid  = threadIdx.x;
  const int lane = tid & 63;
  const int wave = tid >> 6;
  const int quad = lane >> 4;
  const int l15  = lane & 15;
  const int wm   = wave >> 1;
  const int wn   = wave & 1;
  const int m0   = blockIdx.y * 128;
  const int n0   = blockIdx.x * 64;

  f32x4 acc[4][2];
#pragma unroll
  for (int i = 0; i < 4; ++i)
#pragma unroll
    for (int j = 0; j < 2; ++j)
      acc[i][j] = (f32x4){0.f, 0.f, 0.f, 0.f};

  const int srow0 = wave * 8 + (lane >> 3);
  const int cph   = lane & 7;

  for (int kt = 0; kt < 32; ++kt) {
    __syncthreads();
#pragma unroll
    for (int j = 0; j < 4; ++j) {
      const int row = j * 32 + srow0;
      const int gc  = cph ^ (row & 7);
      gload_lds16(A + (size_t)(m0 + row) * 2048 + kt * 64 + gc * 8,
                  &lA[row * 64 + cph * 8]);
    }
#pragma unroll
    for (int j = 0; j < 2; ++j) {
      const int row = j * 32 + srow0;
      const int gc  = cph ^ (row & 7);
      gload_lds16(B + (size_t)(n0 + row) * 2048 + kt * 64 + gc * 8,
                  &lB[row * 64 + cph * 8]);
    }
    __syncthreads();
#pragma unroll
    for (int kk = 0; kk < 2; ++kk) {
      short8 af[4], bfr[2];
#pragma unroll
      for (int i = 0; i < 4; ++i) {
        const int r = wm * 64 + i * 16 + l15;
        af[i] = *(const short8*)&lA[r * 64 + (((kk * 4 + quad) ^ (l15 & 7)) * 8)];
      }
#pragma unroll
      for (int j = 0; j < 2; ++j) {
        const int r = wn * 32 + j * 16 + l15;
        bfr[j] = *(const short8*)&lB[r * 64 + (((kk * 4 + quad) ^ (l15 & 7)) * 8)];
      }
#pragma unroll
      for (int i = 0; i < 4; ++i)
#pragma unroll
        for (int j = 0; j < 2; ++j)
          acc[i][j] = __builtin_amdgcn_mfma_f32_16x16x32_bf16(af[i], bfr[j], acc[i][j], 0, 0, 0);
    }
  }

#pragma unroll
  for (int i = 0; i < 4; ++i)
#pragma unroll
    for (int j = 0; j < 2; ++j)
#pragma unroll
      for (int r = 0; r < 4; ++r) {
        const int row = m0 + wm * 64 + i * 16 + quad * 4 + r;
        const int col = n0 + wn * 32 + j * 16 + l15;
        C[(size_t)row * 2048 + col] = acc[i][j][r];
      }
}

// ===========================================================================
// cvt: fp32 -> bf16 arena [10240][2048] (Wq|Wk|Wv|Wo|hs).
// Blocks >= 10240 build transposed f32 tables cosT/sinT[hd][s] (in d_out).
// ===========================================================================
__global__ __launch_bounds__(256)
void cvt_to_bf16(const float* __restrict__ hs, const float* __restrict__ Wq,
                 const float* __restrict__ Wk, const float* __restrict__ Wv,
                 const float* __restrict__ Wo, ushort* __restrict__ dst,
                 const float* __restrict__ cosb, const float* __restrict__ sinb,
                 float* __restrict__ cosT, float* __restrict__ sinT)
{
  if (blockIdx.x >= 10240) {
    const int b2 = blockIdx.x - 10240;   // [0,256)
    const int d  = b2 & 127;
    const float* src = (b2 < 128) ? cosb : sinb;
    float* dstT      = (b2 < 128) ? cosT : sinT;
#pragma unroll
    for (int kk = 0; kk < 8; ++kk) {
      const int s = kk * 256 + threadIdx.x;
      dstT[d * 2048 + s] = src[s * 128 + d];
    }
    return;
  }
  const size_t base = ((size_t)blockIdx.x * 256 + threadIdx.x) * 8;
  const int row = (int)(base >> 11);
  const int col = (int)(base & 2047);
  const float* src;
  if      (row < 2048) src = Wq + (size_t)row * 2048;
  else if (row < 4096) src = Wk + (size_t)(row - 2048) * 2048;
  else if (row < 6144) src = Wv + (size_t)(row - 4096) * 2048;
  else if (row < 8192) src = Wo + (size_t)(row - 6144) * 2048;
  else                 src = hs + (size_t)(row - 8192) * 2048;
  float4 a = *(const float4*)(src + col);
  float4 b = *(const float4*)(src + col + 4);
  short8 s;
  s[0] = (short)f2b(a.x); s[1] = (short)f2b(a.y);
  s[2] = (short)f2b(a.z); s[3] = (short)f2b(a.w);
  s[4] = (short)f2b(b.x); s[5] = (short)f2b(b.y);
  s[6] = (short)f2b(b.z); s[7] = (short)f2b(b.w);
  *(short8*)(dst + base) = s;
}

// ===========================================================================
// Flash v2: 128-q tiles, 64-key tiles, no running max (log2-unit scores),
// l via ones-column MFMA. Static split-K schedule; single-chunk items write
// normalized output directly; chunked items write partials, combined later.
// ===========================================================================
__device__ const int FA_QT[30]   = {5,11,11,10,10,15,15,4,9,9,13,14,14,14,15,8,8,12,12,13,13,3,7,7,12,6,6,2,1,0};
__device__ const int FA_BEG[30]  = {0,0,12,0,11,10,21,0,0,10,18,0,10,20,0,0,9,8,17,0,9,0,0,8,0,0,7,0,0,0};
__device__ const int FA_END[30]  = {12,12,24,11,22,21,32,10,10,20,28,10,20,30,10,9,18,17,26,9,18,8,8,16,8,7,14,6,4,2};
__device__ const int FA_SLOT[30] = {5,16,17,14,15,28,29,4,12,13,23,24,25,26,27,10,11,19,20,21,22,3,8,9,18,6,7,2,1,0};
__device__ const int FA_OFF[16]  = {0,1,2,3,4,5,6,8,10,12,14,16,18,21,24,27};
__device__ const int FA_NC[16]   = {1,1,1,1,1,1,2,2,2,2,2,2,3,3,3,3};

__global__ __launch_bounds__(256, 2)
void flash_attn2(const ushort* __restrict__ arena,
                 ushort* __restrict__ Ab,
                 ushort* __restrict__ Opart,
                 float* __restrict__ Ml)
{
  __shared__ ushort Kl[64 * 128];
  __shared__ ushort Vt[128 * 64];
  __shared__ ushort Pl[4][32 * 72];

  const int tid  = threadIdx.x;
  const int lane = tid & 63;
  const int w    = tid >> 6;
  const int quad = lane >> 4;
  const int l15  = lane & 15;
  const int h    = blockIdx.y;

  const int item  = blockIdx.x;
  const int qt    = FA_QT[item];
  const int ktBeg = FA_BEG[item];
  const int ktEnd = FA_END[item];
  const int slot  = h * 30 + FA_SLOT[item];

  short8 qa[2][4];
#pragma unroll
  for (int i = 0; i < 2; ++i)
#pragma unroll
    for (int kk = 0; kk < 4; ++kk)
      qa[i][kk] = *(const short8*)(arena +
          (size_t)(qt * 128 + w * 32 + i * 16 + l15) * 6144 + h * HD + kk * 32 + quad * 8);

  f32x4 o[2][8], acc_l[2];
#pragma unroll
  for (int i = 0; i < 2; ++i) {
    acc_l[i] = (f32x4){0.f, 0.f, 0.f, 0.f};
#pragma unroll
    for (int nf = 0; nf < 8; ++nf) o[i][nf] = (f32x4){0.f, 0.f, 0.f, 0.f};
  }

  short8 bones;
#pragma unroll
  for (int e = 0; e < 8; ++e) bones[e] = (short)0x3F80;  // bf16 1.0

  const int ksrow0 = w * 4 + (lane >> 4);
  const int kch    = lane & 15;
  const int vrow0  = w * 8 + (lane >> 3);
  const int vch    = lane & 7;

  for (int kt = ktBeg; kt < ktEnd; ++kt) {
    __syncthreads();

#pragma unroll
    for (int j = 0; j < 4; ++j) {
      const int row = j * 16 + ksrow0;
      const int gc  = kch ^ (row & 15);
      gload_lds16(arena + (size_t)(kt * 64 + row) * 6144 + 2048 + h * HD + gc * 8,
                  &Kl[row * 128 + kch * 8]);
    }
#pragma unroll
    for (int j = 0; j < 4; ++j) {
      const int d  = j * 32 + vrow0;
      const int gc = vch ^ (d & 7);
      gload_lds16(arena + (size_t)(h * HD + d) * 6144 + 4096 + kt * 64 + gc * 8,
                  &Vt[d * 64 + vch * 8]);
    }
    __syncthreads();

    f32x4 sf[2][4];
#pragma unroll
    for (int i = 0; i < 2; ++i)
#pragma unroll
      for (int n = 0; n < 4; ++n) sf[i][n] = (f32x4){0.f, 0.f, 0.f, 0.f};
#pragma unroll
    for (int kk = 0; kk < 4; ++kk)
#pragma unroll
      for (int n = 0; n < 4; ++n) {
        const int key = n * 16 + l15;
        short8 b = *(const short8*)&Kl[key * 128 + (((kk * 4 + quad) ^ l15) * 8)];
#pragma unroll
        for (int i = 0; i < 2; ++i)
          sf[i][n] = __builtin_amdgcn_mfma_f32_16x16x32_bf16(qa[i][kk], b, sf[i][n], 0, 0, 0);
      }

    if (kt >= 2 * qt) {
#pragma unroll
      for (int i = 0; i < 2; ++i)
#pragma unroll
        for (int n = 0; n < 4; ++n)
#pragma unroll
          for (int r = 0; r < 4; ++r) {
            const int key = kt * 64 + n * 16 + l15;
            const int row = qt * 128 + w * 32 + i * 16 + quad * 4 + r;
            if (key > row) sf[i][n][r] = -1e30f;
          }
    }

#pragma unroll
    for (int i = 0; i < 2; ++i)
#pragma unroll
      for (int n = 0; n < 4; ++n)
#pragma unroll
        for (int r = 0; r < 4; ++r)
          Pl[w][(i * 16 + quad * 4 + r) * 72 + n * 16 + l15] = f2b_trunc(exp2f(sf[i][n][r]));

#pragma unroll
    for (int kk = 0; kk < 2; ++kk) {
      short8 pa[2];
#pragma unroll
      for (int i = 0; i < 2; ++i)
        pa[i] = *(const short8*)&Pl[w][(i * 16 + l15) * 72 + kk * 32 + quad * 8];
#pragma unroll
      for (int nf = 0; nf < 8; ++nf) {
        const int d = nf * 16 + l15;
        short8 b = *(const short8*)&Vt[d * 64 + (((kk * 4 + quad) ^ (l15 & 7)) * 8)];
#pragma unroll
        for (int i = 0; i < 2; ++i)
          o[i][nf] = __builtin_amdgcn_mfma_f32_16x16x32_bf16(pa[i], b, o[i][nf], 0, 0, 0);
      }
#pragma unroll
      for (int i = 0; i < 2; ++i)
        acc_l[i] = __builtin_amdgcn_mfma_f32_16x16x32_bf16(pa[i], bones, acc_l[i], 0, 0, 0);
    }
  }

  if (FA_NC[qt] == 1) {
    float inv[2][4];
#pragma unroll
    for (int i = 0; i < 2; ++i)
#pragma unroll
      for (int r = 0; r < 4; ++r) inv[i][r] = 1.0f / acc_l[i][r];
#pragma unroll
    for (int i = 0; i < 2; ++i)
#pragma unroll
      for (int nf = 0; nf < 8; ++nf)
#pragma unroll
        for (int r = 0; r < 4; ++r) {
          const int row = qt * 128 + w * 32 + i * 16 + quad * 4 + r;
          const int col = h * HD + nf * 16 + l15;
          Ab[(size_t)row * 2048 + col] = f2b(o[i][nf][r] * inv[i][r]);
        }
  } else {
    ushort* dst = Opart + (size_t)slot * (128 * 128);
#pragma unroll
    for (int i = 0; i < 2; ++i)
#pragma unroll
      for (int nf = 0; nf < 8; ++nf)
#pragma unroll
        for (int r = 0; r < 4; ++r) {
          const int row = w * 32 + i * 16 + quad * 4 + r;
          const int col = nf * 16 + l15;
          dst[row * 128 + col] = f2b(o[i][nf][r]);
        }
    if (l15 == 0) {
#pragma unroll
      for (int i = 0; i < 2; ++i)
#pragma unroll
        for (int r = 0; r < 4; ++r)
          Ml[(size_t)slot * 128 + w * 32 + i * 16 + quad * 4 + r] = acc_l[i][r];
    }
  }
}

// O(h,qt) = sum_c O_c / sum_c l_c for qt in [6,16)
__global__ __launch_bounds__(256)
void fa_combine2(const ushort* __restrict__ Opart, const float* __restrict__ Ml,
                 ushort* __restrict__ Ab)
{
  const int qt  = 6 + blockIdx.x;
  const int h   = blockIdx.y;
  const int row = threadIdx.x >> 1;
  const int hf  = (threadIdx.x & 1) * 64;
  const int np  = FA_NC[qt];
  const int s0  = h * 30 + FA_OFF[qt];

  float lsum = 0.f;
  for (int c = 0; c < np; ++c) lsum += Ml[(size_t)(s0 + c) * 128 + row];
  const float inv = 1.0f / lsum;

  float acc[64];
#pragma unroll
  for (int e = 0; e < 64; ++e) acc[e] = 0.f;
  for (int c = 0; c < np; ++c) {
    const ushort* src = Opart + (size_t)(s0 + c) * (128 * 128) + row * 128 + hf;
#pragma unroll
    for (int j = 0; j < 8; ++j) {
      short8 x = *(const short8*)(src + j * 8);
#pragma unroll
      for (int e = 0; e < 8; ++e) acc[j * 8 + e] += b2f((ushort)x[e]);
    }
  }
  ushort* d = Ab + (size_t)(qt * 128 + row) * 2048 + h * 128 + hf;
#pragma unroll
  for (int j = 0; j < 8; ++j) {
    short8 y;
#pragma unroll
    for (int e = 0; e < 8; ++e) y[e] = (short)f2b(acc[j * 8 + e] * inv);
    *(short8*)(d + j * 8) = y;
  }
}

// ===========================================================================
// FALLBACK PATH (ws < 64 MB) — R3-proven
// ===========================================================================
template<bool A32, bool B32, bool C32>
__device__ __forceinline__ void gemm_body(const void* __restrict__ Ap,
                                          const void* __restrict__ Bp,
                                          void* __restrict__ Cp)
{
  __shared__ ushort lA[128 * 72];
  __shared__ ushort lB[128 * 72];
  const int tid  = threadIdx.x;
  const int lane = tid & 63;
  const int wave = tid >> 6;
  const int quad = lane >> 4;
  const int l15  = lane & 15;
  const int wm   = wave >> 1;
  const int wn   = wave & 1;
  const int m0   = blockIdx.y * 128;
  const int n0   = blockIdx.x * 128;

  f32x4 acc[4][4];
#pragma unroll
  for (int i = 0; i < 4; ++i)
#pragma unroll
    for (int j = 0; j < 4; ++j)
      acc[i][j] = (f32x4){0.f, 0.f, 0.f, 0.f};

  const int srow = tid >> 1;
  const int scol = (tid & 1) * 32;
  ushort* aL = &lA[srow * 72 + scol];
  ushort* bL = &lB[srow * 72 + scol];

  for (int kt = 0; kt < 32; ++kt) {
    __syncthreads();
    if (A32) {
      const float* g = (const float*)Ap + (size_t)(m0 + srow) * 2048 + kt * 64 + scol;
#pragma unroll
      for (int j = 0; j < 4; ++j) {
        float4 f0 = *(const float4*)(g + 8 * j);
        float4 f1 = *(const float4*)(g + 8 * j + 4);
        short8 sv;
        sv[0] = (short)f2b(f0.x); sv[1] = (short)f2b(f0.y);
        sv[2] = (short)f2b(f0.z); sv[3] = (short)f2b(f0.w);
        sv[4] = (short)f2b(f1.x); sv[5] = (short)f2b(f1.y);
        sv[6] = (short)f2b(f1.z); sv[7] = (short)f2b(f1.w);
        *(short8*)(aL + 8 * j) = sv;
      }
    } else {
      const ushort* g = (const ushort*)Ap + (size_t)(m0 + srow) * 2048 + kt * 64 + scol;
#pragma unroll
      for (int j = 0; j < 4; ++j)
        *(short8*)(aL + 8 * j) = *(const short8*)(g + 8 * j);
    }
    if (B32) {
      const float* g = (const float*)Bp + (size_t)(n0 + srow) * 2048 + kt * 64 + scol;
#pragma unroll
      for (int j = 0; j < 4; ++j) {
        float4 f0 = *(const float4*)(g + 8 * j);
        float4 f1 = *(const float4*)(g + 8 * j + 4);
        short8 sv;
        sv[0] = (short)f2b(f0.x); sv[1] = (short)f2b(f0.y);
        sv[2] = (short)f2b(f0.z); sv[3] = (short)f2b(f0.w);
        sv[4] = (short)f2b(f1.x); sv[5] = (short)f2b(f1.y);
        sv[6] = (short)f2b(f1.z); sv[7] = (short)f2b(f1.w);
        *(short8*)(bL + 8 * j) = sv;
      }
    } else {
      const ushort* g = (const ushort*)Bp + (size_t)(n0 + srow) * 2048 + kt * 64 + scol;
#pragma unroll
      for (int j = 0; j < 4; ++j)
        *(short8*)(bL + 8 * j) = *(const short8*)(g + 8 * j);
    }
    __syncthreads();
#pragma unroll
    for (int kk = 0; kk < 2; ++kk) {
      short8 af[4], bfr[4];
#pragma unroll
      for (int i = 0; i < 4; ++i)
        af[i] = *(const short8*)&lA[(wm * 64 + i * 16 + l15) * 72 + kk * 32 + quad * 8];
#pragma unroll
      for (int j = 0; j < 4; ++j)
        bfr[j] = *(const short8*)&lB[(wn * 64 + j * 16 + l15) * 72 + kk * 32 + quad * 8];
#pragma unroll
      for (int i = 0; i < 4; ++i)
#pragma unroll
        for (int j = 0; j < 4; ++j)
          acc[i][j] = __builtin_amdgcn_mfma_f32_16x16x32_bf16(af[i], bfr[j], acc[i][j], 0, 0, 0);
    }
  }

#pragma unroll
  for (int i = 0; i < 4; ++i)
#pragma unroll
    for (int j = 0; j < 4; ++j)
#pragma unroll
      for (int r = 0; r < 4; ++r) {
        const int row = m0 + wm * 64 + i * 16 + quad * 4 + r;
        const int col = n0 + wn * 64 + j * 16 + l15;
        if (C32) ((float*)Cp)[(size_t)row * 2048 + col] = acc[i][j][r];
        else     ((ushort*)Cp)[(size_t)row * 2048 + col] = f2b(acc[i][j][r]);
      }
}

__global__ __launch_bounds__(256)
void gemm_qkv_f32(const float* __restrict__ A, const float* __restrict__ Bq,
                  const float* __restrict__ Bk, const float* __restrict__ Bv,
                  ushort* __restrict__ Cq, ushort* __restrict__ Ck, ushort* __restrict__ Cv)
{
  const float* B = (blockIdx.z == 0) ? Bq : (blockIdx.z == 1 ? Bk : Bv);
  ushort* C      = (blockIdx.z == 0) ? Cq : (blockIdx.z == 1 ? Ck : Cv);
  gemm_body<true, true, false>(A, B, C);
}

__global__ __launch_bounds__(256)
void gemm_wo_f32(const ushort* __restrict__ A, const float* __restrict__ B,
                 float* __restrict__ C)
{ gemm_body<false, true, true>(A, B, C); }

__global__ __launch_bounds__(256)
void rope_ia3_old(ushort* __restrict__ base, int stride, int koff, int voff,
                  const float* __restrict__ cosb, const float* __restrict__ sinb,
                  const float* __restrict__ lk, const float* __restrict__ lv)
{
  const int s = blockIdx.x;
  const float qscale = 0.08838834764831845f * 1.4426950408889634f;
#pragma unroll
  for (int i = 0; i < 4; ++i) {
    const int p = threadIdx.x + 256 * i;
    const int h = p >> 6;
    const int d = p & 63;
    const size_t lo = (size_t)s * stride + h * HD + d;
    const size_t hi = lo + 64;
    const float c_lo = cosb[s * HD + d];
    const float c_hi = cosb[s * HD + d + 64];
    const float s_lo = sinb[s * HD + d];
    const float s_hi = sinb[s * HD + d + 64];
    ushort* Q = base;
    ushort* K = base + koff;
    ushort* V = base + voff;
    const float qlo = b2f(Q[lo]), qhi = b2f(Q[hi]);
    const float klo = b2f(K[lo]), khi = b2f(K[hi]);
    const float vlo = b2f(V[lo]), vhi = b2f(V[hi]);
    const float rq_lo = qlo * c_lo - qhi * s_lo;
    const float rq_hi = qhi * c_hi + qlo * s_hi;
    const float rk_lo = klo * c_lo - khi * s_lo;
    const float rk_hi = khi * c_hi + klo * s_hi;
    Q[lo] = f2b(rq_lo * lk[h * HD + d]      * qscale);
    Q[hi] = f2b(rq_hi * lk[h * HD + d + 64] * qscale);
    K[lo] = f2b(rk_lo);
    K[hi] = f2b(rk_hi);
    V[lo] = f2b(vlo * lv[h * HD + d]);
    V[hi] = f2b(vhi * lv[h * HD + d + 64]);
  }
}

__global__ __launch_bounds__(256)
void flash_attn_old(const ushort* __restrict__ QKV, int stride, int koff, int voff,
                    ushort* __restrict__ Ob, int ostride)
{
  __shared__ ushort Kl[64 * 128];
  __shared__ ushort Vt[128 * 64];
  __shared__ ushort Pl[4][16 * 72];

  const int tid  = threadIdx.x;
  const int lane = tid & 63;
  const int w    = tid >> 6;
  const int quad = lane >> 4;
  const int l15  = lane & 15;
  const int qt   = (int)gridDim.x - 1 - (int)blockIdx.x;
  const int h    = blockIdx.y;

  const ushort* Q = QKV;
  const ushort* K = QKV + koff;
  const ushort* V = QKV + voff;

  const int qrow = qt * 64 + w * 16 + l15;
  short8 qa[4];
#pragma unroll
  for (int kk = 0; kk < 4; ++kk)
    qa[kk] = *(const short8*)(Q + (size_t)qrow * stride + h * HD + kk * 32 + quad * 8);

  float m_[4], l_[4];
  f32x4 o[8];
#pragma unroll
  for (int r = 0; r < 4; ++r) { m_[r] = -1e30f; l_[r] = 0.f; }
#pragma unroll
  for (int nf = 0; nf < 8; ++nf) o[nf] = (f32x4){0.f, 0.f, 0.f, 0.f};

  const int ksrow0 = w * 4 + (lane >> 4);
  const int kch    = lane & 15;
  const int vkp    = tid & 15;
  const int vd8    = tid >> 4;

  for (int kt = 0; kt <= qt; ++kt) {
    __syncthreads();
#pragma unroll
    for (int j = 0; j < 4; ++j) {
      const int row = j * 16 + ksrow0;
      const int gc  = kch ^ (row & 15);
      gload_lds16(K + (size_t)(kt * 64 + row) * stride + h * HD + gc * 8,
                  &Kl[row * 128 + kch * 8]);
    }
    {
      const ushort* vb = V + (size_t)(kt * 64) * stride + h * HD + vd8 * 8;
      short8 v0 = *(const short8*)(vb + (size_t)(2 * vkp)      * stride);
      short8 v1 = *(const short8*)(vb + (size_t)(2 * vkp + 1)  * stride);
      short8 v2 = *(const short8*)(vb + (size_t)(2 * vkp + 32) * stride);
      short8 v3 = *(const short8*)(vb + (size_t)(2 * vkp + 33) * stride);
      const int wlo = vkp >> 2, woff = 2 * (vkp & 3);
#pragma unroll
      for (int c = 0; c < 8; ++c) {
        const int d = vd8 * 8 + c;
        unsigned int p01 = (ushort)v0[c] | ((unsigned int)(ushort)v1[c] << 16);
        unsigned int p23 = (ushort)v2[c] | ((unsigned int)(ushort)v3[c] << 16);
        *(unsigned int*)&Vt[d * 64 + ((wlo       ^ c) * 8) + woff] = p01;
        *(unsigned int*)&Vt[d * 64 + (((wlo + 4) ^ c) * 8) + woff] = p23;
      }
    }
    __syncthreads();

    f32x4 sf[4];
#pragma unroll
    for (int n = 0; n < 4; ++n) sf[n] = (f32x4){0.f, 0.f, 0.f, 0.f};
#pragma unroll
    for (int kk = 0; kk < 4; ++kk)
#pragma unroll
      for (int n = 0; n < 4; ++n) {
        const int key = n * 16 + l15;
        short8 b = *(const short8*)&Kl[key * 128 + (((kk * 4 + quad) ^ l15) * 8)];
        sf[n] = __builtin_amdgcn_mfma_f32_16x16x32_bf16(qa[kk], b, sf[n], 0, 0, 0);
      }

    if (kt == qt) {
#pragma unroll
      for (int n = 0; n < 4; ++n)
#pragma unroll
        for (int r = 0; r < 4; ++r)
          if (n * 16 + l15 > w * 16 + quad * 4 + r) sf[n][r] = -1e30f;
    }

    float pm[4];
#pragma unroll
    for (int r = 0; r < 4; ++r)
      pm[r] = fmaxf(fmaxf(sf[0][r], sf[1][r]), fmaxf(sf[2][r], sf[3][r]));
#pragma unroll
    for (int off = 1; off < 16; off <<= 1)
#pragma unroll
      for (int r = 0; r < 4; ++r)
        pm[r] = fmaxf(pm[r], __shfl_xor(pm[r], off));

    float al[4], ps[4], p[4][4];
#pragma unroll
    for (int r = 0; r < 4; ++r) {
      const float mn = fmaxf(m_[r], pm[r]);
      al[r] = exp2f(m_[r] - mn);
      m_[r] = mn;
      ps[r] = 0.f;
    }
#pragma unroll
    for (int n = 0; n < 4; ++n)
#pragma unroll
      for (int r = 0; r < 4; ++r) {
        p[n][r] = exp2f(sf[n][r] - m_[r]);
        ps[r] += p[n][r];
      }
#pragma unroll
    for (int off = 1; off < 16; off <<= 1)
#pragma unroll
      for (int r = 0; r < 4; ++r)
        ps[r] += __shfl_xor(ps[r], off);
#pragma unroll
    for (int r = 0; r < 4; ++r) l_[r] = al[r] * l_[r] + ps[r];
#pragma unroll
    for (int nf = 0; nf < 8; ++nf)
#pragma unroll
      for (int r = 0; r < 4; ++r) o[nf][r] *= al[r];

#pragma unroll
    for (int n = 0; n < 4; ++n)
#pragma unroll
      for (int r = 0; r < 4; ++r)
        Pl[w][(quad * 4 + r) * 72 + n * 16 + l15] = f2b(p[n][r]);

#pragma unroll
    for (int kk = 0; kk < 2; ++kk) {
      short8 pa = *(const short8*)&Pl[w][l15 * 72 + kk * 32 + quad * 8];
#pragma unroll
      for (int nf = 0; nf < 8; ++nf) {
        const int d = nf * 16 + l15;
        short8 b = *(const short8*)&Vt[d * 64 + (((kk * 4 + quad) ^ (l15 & 7)) * 8)];
        o[nf] = __builtin_amdgcn_mfma_f32_16x16x32_bf16(pa, b, o[nf], 0, 0, 0);
      }
    }
  }

  float inv[4];
#pragma unroll
  for (int r = 0; r < 4; ++r) inv[r] = 1.0f / l_[r];
#pragma unroll
  for (int nf = 0; nf < 8; ++nf)
#pragma unroll
    for (int r = 0; r < 4; ++r) {
      const int row = qt * 64 + w * 16 + quad * 4 + r;
      const int col = h * HD + nf * 16 + l15;
      Ob[(size_t)row * ostride + col] = f2b(o[nf][r] * inv[r]);
    }
}

// ===========================================================================
extern "C" void kernel_launch(void* const* d_in, const int* in_sizes, int n_in,
                              void* d_out, int out_size, void* d_ws, size_t ws_size,
                              hipStream_t stream)
{
  const float* hs   = (const float*)d_in[0];
  const float* cosb = (const float*)d_in[2];
  const float* sinb = (const float*)d_in[3];
  const float* Wq   = (const float*)d_in[4];
  const float* Wk   = (const float*)d_in[5];
  const float* Wv   = (const float*)d_in[6];
  const float* Wo   = (const float*)d_in[7];
  const float* lk   = (const float*)d_in[8];
  const float* lv   = (const float*)d_in[9];
  float* out = (float*)d_out;

  char* ws = (char*)d_ws;
  const bool fast = ws_size >= (size_t)64 * 1024 * 1024;

  if (fast) {
    // ws: [0,32M) WB bf16 (Wq|Wk|Wv|Wo rows); Wq/Wk/Wv dead after gemm_qkv ->
    //     Opart at WB, Ml at ws+16M. [32,40M) hsB -> Ab. [40,64M) QKV arena.
    // d_out doubles as scratch for cosT/sinT (f32 [128][2048] each) until
    // gemm_wo_64 fully overwrites it.
    ushort* WB    = (ushort*)ws;
    ushort* hsB   = WB + (size_t)8192 * 2048;
    ushort* QKV   = (ushort*)(ws + (size_t)40 * 1024 * 1024);
    ushort* Ab    = hsB;
    ushort* Opart = WB;
    float*  Ml    = (float*)(ws + (size_t)16 * 1024 * 1024);
    float*  cosT  = out;                       // [128][2048] f32, 1 MB
    float*  sinT  = out + (size_t)128 * 2048;  // 1 MB

    cvt_to_bf16<<<dim3(10496), 256, 0, stream>>>(hs, Wq, Wk, Wv, Wo, WB,
                                                 cosb, sinb, cosT, sinT);
    gemm_qkv_b<<<dim3(48, 16), 256, 0, stream>>>(hsB, WB, QKV, lv, cosT, sinT, lk);
    flash_attn2<<<dim3(30, NH), 256, 0, stream>>>(QKV, Ab, Opart, Ml);
    fa_combine2<<<dim3(10, NH), 256, 0, stream>>>(Opart, Ml, Ab);
    gemm_wo_64<<<dim3(32, 16), 256, 0, stream>>>(Ab, WB + (size_t)6144 * 2048, out);
  } else {
    const size_t SZ = (size_t)S_LEN * D_MODEL;
    ushort* Qb = (ushort*)ws;
    ushort* Kb = Qb + SZ;
    ushort* Vb = Qb + 2 * SZ;
    ushort* Ab = Qb;

    gemm_qkv_f32<<<dim3(16, 16, 3), 256, 0, stream>>>(hs, Wq, Wk, Wv, Qb, Kb, Vb);
    rope_ia3_old<<<dim3(S_LEN), 256, 0, stream>>>(Qb, 2048, (int)SZ, (int)(2 * SZ), cosb, sinb, lk, lv);
    flash_attn_old<<<dim3(S_LEN / 64, NH), 256, 0, stream>>>(Qb, 2048, (int)SZ, (int)(2 * SZ), Ab, 2048);
    gemm_wo_f32<<<dim3(16, 16), 256, 0, stream>>>(Ab, Wo, out);
  }
}

// Round 10
// 297.464 us; speedup vs baseline: 1.1235x; 1.1235x over previous
//
#include <hip/hip_runtime.h>

typedef __attribute__((ext_vector_type(8))) short short8;
typedef __attribute__((ext_vector_type(4))) short s16x4;
typedef __attribute__((ext_vector_type(4))) float f32x4;
typedef unsigned short ushort;

#define S_LEN 2048
#define D_MODEL 2048
#define NH 16
#define HD 128

__device__ __forceinline__ float b2f(ushort u) {
  union { unsigned int i; float f; } v; v.i = ((unsigned int)u) << 16; return v.f;
}
__device__ __forceinline__ ushort f2b(float f) {
  union { float f; unsigned int i; } v; v.f = f;
  unsigned int r = v.i + 0x7FFFu + ((v.i >> 16) & 1u);
  return (ushort)(r >> 16);
}
__device__ __forceinline__ ushort f2b_trunc(float f) {
  union { float f; unsigned int i; } v; v.f = f;
  return (ushort)(v.i >> 16);
}

__device__ __forceinline__ void gload_lds16(const void* g, void* l) {
  __builtin_amdgcn_global_load_lds(
      (const __attribute__((address_space(1))) void*)g,
      (__attribute__((address_space(3))) void*)l, 16, 0, 0);
}

// ===========================================================================
// QKV GEMM (bf16, global_load_lds, XOR swizzle). C = A @ B^T, K=2048,
// 128x128 tiles. NO RoPE fusion (measured: fusion costs more inside the
// compute-bound GEMM than the separate 8 µs memory-bound rope kernel).
//   n0 <  4096 (Q/K): bf16 row-major into arena (ld 6144).
//   n0 >= 4096 (V):   V^T write (l_v folded) as (h*128+d)*6144 + 4096 + s.
// ===========================================================================
__global__ __launch_bounds__(256)
void gemm_qkv_b(const ushort* __restrict__ A, const ushort* __restrict__ B,
                ushort* __restrict__ C, const float* __restrict__ lv)
{
  __shared__ ushort lA[128 * 64];
  __shared__ ushort lB[128 * 64];
  const int tid  = threadIdx.x;
  const int lane = tid & 63;
  const int wave = tid >> 6;
  const int quad = lane >> 4;
  const int l15  = lane & 15;
  const int wm   = wave >> 1;
  const int wn   = wave & 1;
  const int m0   = blockIdx.y * 128;
  const int n0   = blockIdx.x * 128;

  f32x4 acc[4][4];
#pragma unroll
  for (int i = 0; i < 4; ++i)
#pragma unroll
    for (int j = 0; j < 4; ++j)
      acc[i][j] = (f32x4){0.f, 0.f, 0.f, 0.f};

  const int srow0 = wave * 8 + (lane >> 3);
  const int cph   = lane & 7;

  for (int kt = 0; kt < 32; ++kt) {
    __syncthreads();
#pragma unroll
    for (int j = 0; j < 4; ++j) {
      const int row = j * 32 + srow0;
      const int gc  = cph ^ (row & 7);
      gload_lds16(A + (size_t)(m0 + row) * 2048 + kt * 64 + gc * 8,
                  &lA[row * 64 + cph * 8]);
      gload_lds16(B + (size_t)(n0 + row) * 2048 + kt * 64 + gc * 8,
                  &lB[row * 64 + cph * 8]);
    }
    __syncthreads();
#pragma unroll
    for (int kk = 0; kk < 2; ++kk) {
      short8 af[4], bfr[4];
#pragma unroll
      for (int i = 0; i < 4; ++i) {
        const int r = wm * 64 + i * 16 + l15;
        af[i] = *(const short8*)&lA[r * 64 + (((kk * 4 + quad) ^ (l15 & 7)) * 8)];
      }
#pragma unroll
      for (int j = 0; j < 4; ++j) {
        const int r = wn * 64 + j * 16 + l15;
        bfr[j] = *(const short8*)&lB[r * 64 + (((kk * 4 + quad) ^ (l15 & 7)) * 8)];
      }
#pragma unroll
      for (int i = 0; i < 4; ++i)
#pragma unroll
        for (int j = 0; j < 4; ++j)
          acc[i][j] = __builtin_amdgcn_mfma_f32_16x16x32_bf16(af[i], bfr[j], acc[i][j], 0, 0, 0);
    }
  }

  if (n0 >= 4096) {
#pragma unroll
    for (int j = 0; j < 4; ++j)
#pragma unroll
      for (int i = 0; i < 4; ++i) {
        const int vcol = n0 - 4096 + wn * 64 + j * 16 + l15;
        const float sc = lv[vcol];
        const int sb   = m0 + wm * 64 + i * 16 + quad * 4;
        s16x4 pk;
#pragma unroll
        for (int r = 0; r < 4; ++r) pk[r] = (short)f2b(acc[i][j][r] * sc);
        *(s16x4*)&C[(size_t)vcol * 6144 + 4096 + sb] = pk;
      }
    return;
  }

#pragma unroll
  for (int i = 0; i < 4; ++i)
#pragma unroll
    for (int j = 0; j < 4; ++j)
#pragma unroll
      for (int r = 0; r < 4; ++r) {
        const int row = m0 + wm * 64 + i * 16 + quad * 4 + r;
        const int col = n0 + wn * 64 + j * 16 + l15;
        C[(size_t)row * 6144 + col] = f2b(acc[i][j][r]);
      }
}

// ===========================================================================
// Output GEMM: 128x64 tiles -> 512 blocks (2/CU), f32 direct store.
// ===========================================================================
__global__ __launch_bounds__(256)
void gemm_wo_64(const ushort* __restrict__ A, const ushort* __restrict__ B,
                float* __restrict__ C)
{
  __shared__ ushort lA[128 * 64];
  __shared__ ushort lB[64 * 64];
  const int tid  = threadIdx.x;
  const int lane = tid & 63;
  const int wave = tid >> 6;
  const int quad = lane >> 4;
  const int l15  = lane & 15;
  const int wm   = wave >> 1;
  const int wn   = wave & 1;
  const int m0   = blockIdx.y * 128;
  const int n0   = blockIdx.x * 64;

  f32x4 acc[4][2];
#pragma unroll
  for (int i = 0; i < 4; ++i)
#pragma unroll
    for (int j = 0; j < 2; ++j)
      acc[i][j] = (f32x4){0.f, 0.f, 0.f, 0.f};

  const int srow0 = wave * 8 + (lane >> 3);
  const int cph   = lane & 7;

  for (int kt = 0; kt < 32; ++kt) {
    __syncthreads();
#pragma unroll
    for (int j = 0; j < 4; ++j) {
      const int row = j * 32 + srow0;
      const int gc  = cph ^ (row & 7);
      gload_lds16(A + (size_t)(m0 + row) * 2048 + kt * 64 + gc * 8,
                  &lA[row * 64 + cph * 8]);
    }
#pragma unroll
    for (int j = 0; j < 2; ++j) {
      const int row = j * 32 + srow0;
      const int gc  = cph ^ (row & 7);
      gload_lds16(B + (size_t)(n0 + row) * 2048 + kt * 64 + gc * 8,
                  &lB[row * 64 + cph * 8]);
    }
    __syncthreads();
#pragma unroll
    for (int kk = 0; kk < 2; ++kk) {
      short8 af[4], bfr[2];
#pragma unroll
      for (int i = 0; i < 4; ++i) {
        const int r = wm * 64 + i * 16 + l15;
        af[i] = *(const short8*)&lA[r * 64 + (((kk * 4 + quad) ^ (l15 & 7)) * 8)];
      }
#pragma unroll
      for (int j = 0; j < 2; ++j) {
        const int r = wn * 32 + j * 16 + l15;
        bfr[j] = *(const short8*)&lB[r * 64 + (((kk * 4 + quad) ^ (l15 & 7)) * 8)];
      }
#pragma unroll
      for (int i = 0; i < 4; ++i)
#pragma unroll
        for (int j = 0; j < 2; ++j)
          acc[i][j] = __builtin_amdgcn_mfma_f32_16x16x32_bf16(af[i], bfr[j], acc[i][j], 0, 0, 0);
    }
  }

#pragma unroll
  for (int i = 0; i < 4; ++i)
#pragma unroll
    for (int j = 0; j < 2; ++j)
#pragma unroll
      for (int r = 0; r < 4; ++r) {
        const int row = m0 + wm * 64 + i * 16 + quad * 4 + r;
        const int col = n0 + wn * 32 + j * 16 + l15;
        C[(size_t)row * 2048 + col] = acc[i][j][r];
      }
}

// ===========================================================================
// cvt: fp32 -> bf16 arena [10240][2048] (Wq|Wk|Wv|Wo|hs).
// ===========================================================================
__global__ __launch_bounds__(256)
void cvt_to_bf16(const float* __restrict__ hs, const float* __restrict__ Wq,
                 const float* __restrict__ Wk, const float* __restrict__ Wv,
                 const float* __restrict__ Wo, ushort* __restrict__ dst)
{
  const size_t base = ((size_t)blockIdx.x * 256 + threadIdx.x) * 8;
  const int row = (int)(base >> 11);
  const int col = (int)(base & 2047);
  const float* src;
  if      (row < 2048) src = Wq + (size_t)row * 2048;
  else if (row < 4096) src = Wk + (size_t)(row - 2048) * 2048;
  else if (row < 6144) src = Wv + (size_t)(row - 4096) * 2048;
  else if (row < 8192) src = Wo + (size_t)(row - 6144) * 2048;
  else                 src = hs + (size_t)(row - 8192) * 2048;
  float4 a = *(const float4*)(src + col);
  float4 b = *(const float4*)(src + col + 4);
  short8 s;
  s[0] = (short)f2b(a.x); s[1] = (short)f2b(a.y);
  s[2] = (short)f2b(a.z); s[3] = (short)f2b(a.w);
  s[4] = (short)f2b(b.x); s[5] = (short)f2b(b.y);
  s[6] = (short)f2b(b.z); s[7] = (short)f2b(b.w);
  *(short8*)(dst + base) = s;
}

// ===========================================================================
// RoPE(Q,K) + IA3(Q) + scale fold (1/sqrt(128)*log2e), in place on arena.
// ===========================================================================
__global__ __launch_bounds__(256)
void rope_qk(ushort* __restrict__ arena,
             const float* __restrict__ cosb, const float* __restrict__ sinb,
             const float* __restrict__ lk)
{
  const int s = blockIdx.x;
  const float qscale = 0.08838834764831845f * 1.4426950408889634f;
#pragma unroll
  for (int i = 0; i < 4; ++i) {
    const int p = threadIdx.x + 256 * i;
    const int h = p >> 6;
    const int d = p & 63;

    const size_t qlo_i = (size_t)s * 6144 + h * HD + d;
    const size_t klo_i = qlo_i + 2048;
    const float c_lo = cosb[s * HD + d];
    const float c_hi = cosb[s * HD + d + 64];
    const float s_lo = sinb[s * HD + d];
    const float s_hi = sinb[s * HD + d + 64];

    const float qlo = b2f(arena[qlo_i]), qhi = b2f(arena[qlo_i + 64]);
    const float klo = b2f(arena[klo_i]), khi = b2f(arena[klo_i + 64]);

    const float rq_lo = qlo * c_lo - qhi * s_lo;
    const float rq_hi = qhi * c_hi + qlo * s_hi;
    const float rk_lo = klo * c_lo - khi * s_lo;
    const float rk_hi = khi * c_hi + klo * s_hi;

    arena[qlo_i]      = f2b(rq_lo * lk[h * HD + d]      * qscale);
    arena[qlo_i + 64] = f2b(rq_hi * lk[h * HD + d + 64] * qscale);
    arena[klo_i]      = f2b(rk_lo);
    arena[klo_i + 64] = f2b(rk_hi);
  }
}

// ===========================================================================
// Flash v2: 128-q tiles, 64-key tiles, no running max (log2-unit scores),
// l via ones-column MFMA. Static split-K schedule; single-chunk items write
// normalized output directly; chunked items write partials, combined later.
// ===========================================================================
__device__ const int FA_QT[30]   = {5,11,11,10,10,15,15,4,9,9,13,14,14,14,15,8,8,12,12,13,13,3,7,7,12,6,6,2,1,0};
__device__ const int FA_BEG[30]  = {0,0,12,0,11,10,21,0,0,10,18,0,10,20,0,0,9,8,17,0,9,0,0,8,0,0,7,0,0,0};
__device__ const int FA_END[30]  = {12,12,24,11,22,21,32,10,10,20,28,10,20,30,10,9,18,17,26,9,18,8,8,16,8,7,14,6,4,2};
__device__ const int FA_SLOT[30] = {5,16,17,14,15,28,29,4,12,13,23,24,25,26,27,10,11,19,20,21,22,3,8,9,18,6,7,2,1,0};
__device__ const int FA_OFF[16]  = {0,1,2,3,4,5,6,8,10,12,14,16,18,21,24,27};
__device__ const int FA_NC[16]   = {1,1,1,1,1,1,2,2,2,2,2,2,3,3,3,3};

__global__ __launch_bounds__(256, 2)
void flash_attn2(const ushort* __restrict__ arena,
                 ushort* __restrict__ Ab,
                 ushort* __restrict__ Opart,
                 float* __restrict__ Ml)
{
  __shared__ ushort Kl[64 * 128];
  __shared__ ushort Vt[128 * 64];
  __shared__ ushort Pl[4][32 * 72];

  const int tid  = threadIdx.x;
  const int lane = tid & 63;
  const int w    = tid >> 6;
  const int quad = lane >> 4;
  const int l15  = lane & 15;
  const int h    = blockIdx.y;

  const int item  = blockIdx.x;
  const int qt    = FA_QT[item];
  const int ktBeg = FA_BEG[item];
  const int ktEnd = FA_END[item];
  const int slot  = h * 30 + FA_SLOT[item];

  short8 qa[2][4];
#pragma unroll
  for (int i = 0; i < 2; ++i)
#pragma unroll
    for (int kk = 0; kk < 4; ++kk)
      qa[i][kk] = *(const short8*)(arena +
          (size_t)(qt * 128 + w * 32 + i * 16 + l15) * 6144 + h * HD + kk * 32 + quad * 8);

  f32x4 o[2][8], acc_l[2];
#pragma unroll
  for (int i = 0; i < 2; ++i) {
    acc_l[i] = (f32x4){0.f, 0.f, 0.f, 0.f};
#pragma unroll
    for (int nf = 0; nf < 8; ++nf) o[i][nf] = (f32x4){0.f, 0.f, 0.f, 0.f};
  }

  short8 bones;
#pragma unroll
  for (int e = 0; e < 8; ++e) bones[e] = (short)0x3F80;  // bf16 1.0

  const int ksrow0 = w * 4 + (lane >> 4);
  const int kch    = lane & 15;
  const int vrow0  = w * 8 + (lane >> 3);
  const int vch    = lane & 7;

  for (int kt = ktBeg; kt < ktEnd; ++kt) {
    __syncthreads();

#pragma unroll
    for (int j = 0; j < 4; ++j) {
      const int row = j * 16 + ksrow0;
      const int gc  = kch ^ (row & 15);
      gload_lds16(arena + (size_t)(kt * 64 + row) * 6144 + 2048 + h * HD + gc * 8,
                  &Kl[row * 128 + kch * 8]);
    }
#pragma unroll
    for (int j = 0; j < 4; ++j) {
      const int d  = j * 32 + vrow0;
      const int gc = vch ^ (d & 7);
      gload_lds16(arena + (size_t)(h * HD + d) * 6144 + 4096 + kt * 64 + gc * 8,
                  &Vt[d * 64 + vch * 8]);
    }
    __syncthreads();

    f32x4 sf[2][4];
#pragma unroll
    for (int i = 0; i < 2; ++i)
#pragma unroll
      for (int n = 0; n < 4; ++n) sf[i][n] = (f32x4){0.f, 0.f, 0.f, 0.f};
#pragma unroll
    for (int kk = 0; kk < 4; ++kk)
#pragma unroll
      for (int n = 0; n < 4; ++n) {
        const int key = n * 16 + l15;
        short8 b = *(const short8*)&Kl[key * 128 + (((kk * 4 + quad) ^ l15) * 8)];
#pragma unroll
        for (int i = 0; i < 2; ++i)
          sf[i][n] = __builtin_amdgcn_mfma_f32_16x16x32_bf16(qa[i][kk], b, sf[i][n], 0, 0, 0);
      }

    if (kt >= 2 * qt) {
#pragma unroll
      for (int i = 0; i < 2; ++i)
#pragma unroll
        for (int n = 0; n < 4; ++n)
#pragma unroll
          for (int r = 0; r < 4; ++r) {
            const int key = kt * 64 + n * 16 + l15;
            const int row = qt * 128 + w * 32 + i * 16 + quad * 4 + r;
            if (key > row) sf[i][n][r] = -1e30f;
          }
    }

#pragma unroll
    for (int i = 0; i < 2; ++i)
#pragma unroll
      for (int n = 0; n < 4; ++n)
#pragma unroll
        for (int r = 0; r < 4; ++r)
          Pl[w][(i * 16 + quad * 4 + r) * 72 + n * 16 + l15] = f2b_trunc(exp2f(sf[i][n][r]));

#pragma unroll
    for (int kk = 0; kk < 2; ++kk) {
      short8 pa[2];
#pragma unroll
      for (int i = 0; i < 2; ++i)
        pa[i] = *(const short8*)&Pl[w][(i * 16 + l15) * 72 + kk * 32 + quad * 8];
#pragma unroll
      for (int nf = 0; nf < 8; ++nf) {
        const int d = nf * 16 + l15;
        short8 b = *(const short8*)&Vt[d * 64 + (((kk * 4 + quad) ^ (l15 & 7)) * 8)];
#pragma unroll
        for (int i = 0; i < 2; ++i)
          o[i][nf] = __builtin_amdgcn_mfma_f32_16x16x32_bf16(pa[i], b, o[i][nf], 0, 0, 0);
      }
#pragma unroll
      for (int i = 0; i < 2; ++i)
        acc_l[i] = __builtin_amdgcn_mfma_f32_16x16x32_bf16(pa[i], bones, acc_l[i], 0, 0, 0);
    }
  }

  if (FA_NC[qt] == 1) {
    float inv[2][4];
#pragma unroll
    for (int i = 0; i < 2; ++i)
#pragma unroll
      for (int r = 0; r < 4; ++r) inv[i][r] = 1.0f / acc_l[i][r];
#pragma unroll
    for (int i = 0; i < 2; ++i)
#pragma unroll
      for (int nf = 0; nf < 8; ++nf)
#pragma unroll
        for (int r = 0; r < 4; ++r) {
          const int row = qt * 128 + w * 32 + i * 16 + quad * 4 + r;
          const int col = h * HD + nf * 16 + l15;
          Ab[(size_t)row * 2048 + col] = f2b(o[i][nf][r] * inv[i][r]);
        }
  } else {
    ushort* dst = Opart + (size_t)slot * (128 * 128);
#pragma unroll
    for (int i = 0; i < 2; ++i)
#pragma unroll
      for (int nf = 0; nf < 8; ++nf)
#pragma unroll
        for (int r = 0; r < 4; ++r) {
          const int row = w * 32 + i * 16 + quad * 4 + r;
          const int col = nf * 16 + l15;
          dst[row * 128 + col] = f2b(o[i][nf][r]);
        }
    if (l15 == 0) {
#pragma unroll
      for (int i = 0; i < 2; ++i)
#pragma unroll
        for (int r = 0; r < 4; ++r)
          Ml[(size_t)slot * 128 + w * 32 + i * 16 + quad * 4 + r] = acc_l[i][r];
    }
  }
}

// O(h,qt) = sum_c O_c / sum_c l_c for qt in [6,16)
__global__ __launch_bounds__(256)
void fa_combine2(const ushort* __restrict__ Opart, const float* __restrict__ Ml,
                 ushort* __restrict__ Ab)
{
  const int qt  = 6 + blockIdx.x;
  const int h   = blockIdx.y;
  const int row = threadIdx.x >> 1;
  const int hf  = (threadIdx.x & 1) * 64;
  const int np  = FA_NC[qt];
  const int s0  = h * 30 + FA_OFF[qt];

  float lsum = 0.f;
  for (int c = 0; c < np; ++c) lsum += Ml[(size_t)(s0 + c) * 128 + row];
  const float inv = 1.0f / lsum;

  float acc[64];
#pragma unroll
  for (int e = 0; e < 64; ++e) acc[e] = 0.f;
  for (int c = 0; c < np; ++c) {
    const ushort* src = Opart + (size_t)(s0 + c) * (128 * 128) + row * 128 + hf;
#pragma unroll
    for (int j = 0; j < 8; ++j) {
      short8 x = *(const short8*)(src + j * 8);
#pragma unroll
      for (int e = 0; e < 8; ++e) acc[j * 8 + e] += b2f((ushort)x[e]);
    }
  }
  ushort* d = Ab + (size_t)(qt * 128 + row) * 2048 + h * 128 + hf;
#pragma unroll
  for (int j = 0; j < 8; ++j) {
    short8 y;
#pragma unroll
    for (int e = 0; e < 8; ++e) y[e] = (short)f2b(acc[j * 8 + e] * inv);
    *(short8*)(d + j * 8) = y;
  }
}

// ===========================================================================
// FALLBACK PATH (ws < 64 MB) — R3-proven
// ===========================================================================
template<bool A32, bool B32, bool C32>
__device__ __forceinline__ void gemm_body(const void* __restrict__ Ap,
                                          const void* __restrict__ Bp,
                                          void* __restrict__ Cp)
{
  __shared__ ushort lA[128 * 72];
  __shared__ ushort lB[128 * 72];
  const int tid  = threadIdx.x;
  const int lane = tid & 63;
  const int wave = tid >> 6;
  const int quad = lane >> 4;
  const int l15  = lane & 15;
  const int wm   = wave >> 1;
  const int wn   = wave & 1;
  const int m0   = blockIdx.y * 128;
  const int n0   = blockIdx.x * 128;

  f32x4 acc[4][4];
#pragma unroll
  for (int i = 0; i < 4; ++i)
#pragma unroll
    for (int j = 0; j < 4; ++j)
      acc[i][j] = (f32x4){0.f, 0.f, 0.f, 0.f};

  const int srow = tid >> 1;
  const int scol = (tid & 1) * 32;
  ushort* aL = &lA[srow * 72 + scol];
  ushort* bL = &lB[srow * 72 + scol];

  for (int kt = 0; kt < 32; ++kt) {
    __syncthreads();
    if (A32) {
      const float* g = (const float*)Ap + (size_t)(m0 + srow) * 2048 + kt * 64 + scol;
#pragma unroll
      for (int j = 0; j < 4; ++j) {
        float4 f0 = *(const float4*)(g + 8 * j);
        float4 f1 = *(const float4*)(g + 8 * j + 4);
        short8 sv;
        sv[0] = (short)f2b(f0.x); sv[1] = (short)f2b(f0.y);
        sv[2] = (short)f2b(f0.z); sv[3] = (short)f2b(f0.w);
        sv[4] = (short)f2b(f1.x); sv[5] = (short)f2b(f1.y);
        sv[6] = (short)f2b(f1.z); sv[7] = (short)f2b(f1.w);
        *(short8*)(aL + 8 * j) = sv;
      }
    } else {
      const ushort* g = (const ushort*)Ap + (size_t)(m0 + srow) * 2048 + kt * 64 + scol;
#pragma unroll
      for (int j = 0; j < 4; ++j)
        *(short8*)(aL + 8 * j) = *(const short8*)(g + 8 * j);
    }
    if (B32) {
      const float* g = (const float*)Bp + (size_t)(n0 + srow) * 2048 + kt * 64 + scol;
#pragma unroll
      for (int j = 0; j < 4; ++j) {
        float4 f0 = *(const float4*)(g + 8 * j);
        float4 f1 = *(const float4*)(g + 8 * j + 4);
        short8 sv;
        sv[0] = (short)f2b(f0.x); sv[1] = (short)f2b(f0.y);
        sv[2] = (short)f2b(f0.z); sv[3] = (short)f2b(f0.w);
        sv[4] = (short)f2b(f1.x); sv[5] = (short)f2b(f1.y);
        sv[6] = (short)f2b(f1.z); sv[7] = (short)f2b(f1.w);
        *(short8*)(bL + 8 * j) = sv;
      }
    } else {
      const ushort* g = (const ushort*)Bp + (size_t)(n0 + srow) * 2048 + kt * 64 + scol;
#pragma unroll
      for (int j = 0; j < 4; ++j)
        *(short8*)(bL + 8 * j) = *(const short8*)(g + 8 * j);
    }
    __syncthreads();
#pragma unroll
    for (int kk = 0; kk < 2; ++kk) {
      short8 af[4], bfr[4];
#pragma unroll
      for (int i = 0; i < 4; ++i)
        af[i] = *(const short8*)&lA[(wm * 64 + i * 16 + l15) * 72 + kk * 32 + quad * 8];
#pragma unroll
      for (int j = 0; j < 4; ++j)
        bfr[j] = *(const short8*)&lB[(wn * 64 + j * 16 + l15) * 72 + kk * 32 + quad * 8];
#pragma unroll
      for (int i = 0; i < 4; ++i)
#pragma unroll
        for (int j = 0; j < 4; ++j)
          acc[i][j] = __builtin_amdgcn_mfma_f32_16x16x32_bf16(af[i], bfr[j], acc[i][j], 0, 0, 0);
    }
  }

#pragma unroll
  for (int i = 0; i < 4; ++i)
#pragma unroll
    for (int j = 0; j < 4; ++j)
#pragma unroll
      for (int r = 0; r < 4; ++r) {
        const int row = m0 + wm * 64 + i * 16 + quad * 4 + r;
        const int col = n0 + wn * 64 + j * 16 + l15;
        if (C32) ((float*)Cp)[(size_t)row * 2048 + col] = acc[i][j][r];
        else     ((ushort*)Cp)[(size_t)row * 2048 + col] = f2b(acc[i][j][r]);
      }
}

__global__ __launch_bounds__(256)
void gemm_qkv_f32(const float* __restrict__ A, const float* __restrict__ Bq,
                  const float* __restrict__ Bk, const float* __restrict__ Bv,
                  ushort* __restrict__ Cq, ushort* __restrict__ Ck, ushort* __restrict__ Cv)
{
  const float* B = (blockIdx.z == 0) ? Bq : (blockIdx.z == 1 ? Bk : Bv);
  ushort* C      = (blockIdx.z == 0) ? Cq : (blockIdx.z == 1 ? Ck : Cv);
  gemm_body<true, true, false>(A, B, C);
}

__global__ __launch_bounds__(256)
void gemm_wo_f32(const ushort* __restrict__ A, const float* __restrict__ B,
                 float* __restrict__ C)
{ gemm_body<false, true, true>(A, B, C); }

__global__ __launch_bounds__(256)
void rope_ia3_old(ushort* __restrict__ base, int stride, int koff, int voff,
                  const float* __restrict__ cosb, const float* __restrict__ sinb,
                  const float* __restrict__ lk, const float* __restrict__ lv)
{
  const int s = blockIdx.x;
  const float qscale = 0.08838834764831845f * 1.4426950408889634f;
#pragma unroll
  for (int i = 0; i < 4; ++i) {
    const int p = threadIdx.x + 256 * i;
    const int h = p >> 6;
    const int d = p & 63;
    const size_t lo = (size_t)s * stride + h * HD + d;
    const size_t hi = lo + 64;
    const float c_lo = cosb[s * HD + d];
    const float c_hi = cosb[s * HD + d + 64];
    const float s_lo = sinb[s * HD + d];
    const float s_hi = sinb[s * HD + d + 64];
    ushort* Q = base;
    ushort* K = base + koff;
    ushort* V = base + voff;
    const float qlo = b2f(Q[lo]), qhi = b2f(Q[hi]);
    const float klo = b2f(K[lo]), khi = b2f(K[hi]);
    const float vlo = b2f(V[lo]), vhi = b2f(V[hi]);
    const float rq_lo = qlo * c_lo - qhi * s_lo;
    const float rq_hi = qhi * c_hi + qlo * s_hi;
    const float rk_lo = klo * c_lo - khi * s_lo;
    const float rk_hi = khi * c_hi + klo * s_hi;
    Q[lo] = f2b(rq_lo * lk[h * HD + d]      * qscale);
    Q[hi] = f2b(rq_hi * lk[h * HD + d + 64] * qscale);
    K[lo] = f2b(rk_lo);
    K[hi] = f2b(rk_hi);
    V[lo] = f2b(vlo * lv[h * HD + d]);
    V[hi] = f2b(vhi * lv[h * HD + d + 64]);
  }
}

__global__ __launch_bounds__(256)
void flash_attn_old(const ushort* __restrict__ QKV, int stride, int koff, int voff,
                    ushort* __restrict__ Ob, int ostride)
{
  __shared__ ushort Kl[64 * 128];
  __shared__ ushort Vt[128 * 64];
  __shared__ ushort Pl[4][16 * 72];

  const int tid  = threadIdx.x;
  const int lane = tid & 63;
  const int w    = tid >> 6;
  const int quad = lane >> 4;
  const int l15  = lane & 15;
  const int qt   = (int)gridDim.x - 1 - (int)blockIdx.x;
  const int h    = blockIdx.y;

  const ushort* Q = QKV;
  const ushort* K = QKV + koff;
  const ushort* V = QKV + voff;

  const int qrow = qt * 64 + w * 16 + l15;
  short8 qa[4];
#pragma unroll
  for (int kk = 0; kk < 4; ++kk)
    qa[kk] = *(const short8*)(Q + (size_t)qrow * stride + h * HD + kk * 32 + quad * 8);

  float m_[4], l_[4];
  f32x4 o[8];
#pragma unroll
  for (int r = 0; r < 4; ++r) { m_[r] = -1e30f; l_[r] = 0.f; }
#pragma unroll
  for (int nf = 0; nf < 8; ++nf) o[nf] = (f32x4){0.f, 0.f, 0.f, 0.f};

  const int ksrow0 = w * 4 + (lane >> 4);
  const int kch    = lane & 15;
  const int vkp    = tid & 15;
  const int vd8    = tid >> 4;

  for (int kt = 0; kt <= qt; ++kt) {
    __syncthreads();
#pragma unroll
    for (int j = 0; j < 4; ++j) {
      const int row = j * 16 + ksrow0;
      const int gc  = kch ^ (row & 15);
      gload_lds16(K + (size_t)(kt * 64 + row) * stride + h * HD + gc * 8,
                  &Kl[row * 128 + kch * 8]);
    }
    {
      const ushort* vb = V + (size_t)(kt * 64) * stride + h * HD + vd8 * 8;
      short8 v0 = *(const short8*)(vb + (size_t)(2 * vkp)      * stride);
      short8 v1 = *(const short8*)(vb + (size_t)(2 * vkp + 1)  * stride);
      short8 v2 = *(const short8*)(vb + (size_t)(2 * vkp + 32) * stride);
      short8 v3 = *(const short8*)(vb + (size_t)(2 * vkp + 33) * stride);
      const int wlo = vkp >> 2, woff = 2 * (vkp & 3);
#pragma unroll
      for (int c = 0; c < 8; ++c) {
        const int d = vd8 * 8 + c;
        unsigned int p01 = (ushort)v0[c] | ((unsigned int)(ushort)v1[c] << 16);
        unsigned int p23 = (ushort)v2[c] | ((unsigned int)(ushort)v3[c] << 16);
        *(unsigned int*)&Vt[d * 64 + ((wlo       ^ c) * 8) + woff] = p01;
        *(unsigned int*)&Vt[d * 64 + (((wlo + 4) ^ c) * 8) + woff] = p23;
      }
    }
    __syncthreads();

    f32x4 sf[4];
#pragma unroll
    for (int n = 0; n < 4; ++n) sf[n] = (f32x4){0.f, 0.f, 0.f, 0.f};
#pragma unroll
    for (int kk = 0; kk < 4; ++kk)
#pragma unroll
      for (int n = 0; n < 4; ++n) {
        const int key = n * 16 + l15;
        short8 b = *(const short8*)&Kl[key * 128 + (((kk * 4 + quad) ^ l15) * 8)];
        sf[n] = __builtin_amdgcn_mfma_f32_16x16x32_bf16(qa[kk], b, sf[n], 0, 0, 0);
      }

    if (kt == qt) {
#pragma unroll
      for (int n = 0; n < 4; ++n)
#pragma unroll
        for (int r = 0; r < 4; ++r)
          if (n * 16 + l15 > w * 16 + quad * 4 + r) sf[n][r] = -1e30f;
    }

    float pm[4];
#pragma unroll
    for (int r = 0; r < 4; ++r)
      pm[r] = fmaxf(fmaxf(sf[0][r], sf[1][r]), fmaxf(sf[2][r], sf[3][r]));
#pragma unroll
    for (int off = 1; off < 16; off <<= 1)
#pragma unroll
      for (int r = 0; r < 4; ++r)
        pm[r] = fmaxf(pm[r], __shfl_xor(pm[r], off));

    float al[4], ps[4], p[4][4];
#pragma unroll
    for (int r = 0; r < 4; ++r) {
      const float mn = fmaxf(m_[r], pm[r]);
      al[r] = exp2f(m_[r] - mn);
      m_[r] = mn;
      ps[r] = 0.f;
    }
#pragma unroll
    for (int n = 0; n < 4; ++n)
#pragma unroll
      for (int r = 0; r < 4; ++r) {
        p[n][r] = exp2f(sf[n][r] - m_[r]);
        ps[r] += p[n][r];
      }
#pragma unroll
    for (int off = 1; off < 16; off <<= 1)
#pragma unroll
      for (int r = 0; r < 4; ++r)
        ps[r] += __shfl_xor(ps[r], off);
#pragma unroll
    for (int r = 0; r < 4; ++r) l_[r] = al[r] * l_[r] + ps[r];
#pragma unroll
    for (int nf = 0; nf < 8; ++nf)
#pragma unroll
      for (int r = 0; r < 4; ++r) o[nf][r] *= al[r];

#pragma unroll
    for (int n = 0; n < 4; ++n)
#pragma unroll
      for (int r = 0; r < 4; ++r)
        Pl[w][(quad * 4 + r) * 72 + n * 16 + l15] = f2b(p[n][r]);

#pragma unroll
    for (int kk = 0; kk < 2; ++kk) {
      short8 pa = *(const short8*)&Pl[w][l15 * 72 + kk * 32 + quad * 8];
#pragma unroll
      for (int nf = 0; nf < 8; ++nf) {
        const int d = nf * 16 + l15;
        short8 b = *(const short8*)&Vt[d * 64 + (((kk * 4 + quad) ^ (l15 & 7)) * 8)];
        o[nf] = __builtin_amdgcn_mfma_f32_16x16x32_bf16(pa, b, o[nf], 0, 0, 0);
      }
    }
  }

  float inv[4];
#pragma unroll
  for (int r = 0; r < 4; ++r) inv[r] = 1.0f / l_[r];
#pragma unroll
  for (int nf = 0; nf < 8; ++nf)
#pragma unroll
    for (int r = 0; r < 4; ++r) {
      const int row = qt * 64 + w * 16 + quad * 4 + r;
      const int col = h * HD + nf * 16 + l15;
      Ob[(size_t)row * ostride + col] = f2b(o[nf][r] * inv[r]);
    }
}

// ===========================================================================
extern "C" void kernel_launch(void* const* d_in, const int* in_sizes, int n_in,
                              void* d_out, int out_size, void* d_ws, size_t ws_size,
                              hipStream_t stream)
{
  const float* hs   = (const float*)d_in[0];
  const float* cosb = (const float*)d_in[2];
  const float* sinb = (const float*)d_in[3];
  const float* Wq   = (const float*)d_in[4];
  const float* Wk   = (const float*)d_in[5];
  const float* Wv   = (const float*)d_in[6];
  const float* Wo   = (const float*)d_in[7];
  const float* lk   = (const float*)d_in[8];
  const float* lv   = (const float*)d_in[9];
  float* out = (float*)d_out;

  char* ws = (char*)d_ws;
  const bool fast = ws_size >= (size_t)64 * 1024 * 1024;

  if (fast) {
    // ws: [0,32M) WB bf16 (Wq|Wk|Wv|Wo rows); Wq/Wk/Wv dead after gemm_qkv ->
    //     Opart at WB, Ml at ws+16M. [32,40M) hsB -> Ab. [40,64M) QKV arena:
    //     Q cols 0..2047 | K 2048..4095 | V^T remap (h*128+d)*6144+4096+s.
    ushort* WB    = (ushort*)ws;
    ushort* hsB   = WB + (size_t)8192 * 2048;
    ushort* QKV   = (ushort*)(ws + (size_t)40 * 1024 * 1024);
    ushort* Ab    = hsB;
    ushort* Opart = WB;
    float*  Ml    = (float*)(ws + (size_t)16 * 1024 * 1024);

    cvt_to_bf16<<<dim3(10240), 256, 0, stream>>>(hs, Wq, Wk, Wv, Wo, WB);
    gemm_qkv_b<<<dim3(48, 16), 256, 0, stream>>>(hsB, WB, QKV, lv);
    rope_qk<<<dim3(S_LEN), 256, 0, stream>>>(QKV, cosb, sinb, lk);
    flash_attn2<<<dim3(30, NH), 256, 0, stream>>>(QKV, Ab, Opart, Ml);
    fa_combine2<<<dim3(10, NH), 256, 0, stream>>>(Opart, Ml, Ab);
    gemm_wo_64<<<dim3(32, 16), 256, 0, stream>>>(Ab, WB + (size_t)6144 * 2048, out);
  } else {
    const size_t SZ = (size_t)S_LEN * D_MODEL;
    ushort* Qb = (ushort*)ws;
    ushort* Kb = Qb + SZ;
    ushort* Vb = Qb + 2 * SZ;
    ushort* Ab = Qb;

    gemm_qkv_f32<<<dim3(16, 16, 3), 256, 0, stream>>>(hs, Wq, Wk, Wv, Qb, Kb, Vb);
    rope_ia3_old<<<dim3(S_LEN), 256, 0, stream>>>(Qb, 2048, (int)SZ, (int)(2 * SZ), cosb, sinb, lk, lv);
    flash_attn_old<<<dim3(S_LEN / 64, NH), 256, 0, stream>>>(Qb, 2048, (int)SZ, (int)(2 * SZ), Ab, 2048);
    gemm_wo_f32<<<dim3(16, 16), 256, 0, stream>>>(Ab, Wo, out);
  }
}